// Round 2
// baseline (4388.832 us; speedup 1.0000x reference)
//
#include <hip/hip_runtime.h>
#include <math.h>

#define B_    16
#define BCH   4            // batch chunk
#define T_    4096
#define C_    256
#define CIN1  80
#define EMB   128
#define STRIDE_ 12
#define TP    341
#define NPOS  (B_*TP)      // 5456
#define NQ_   8
#define KCB   256
#define BN_EPS 1e-5

// ---------------- workspace layout (bytes), all doubles ----------------
#define WS_X1D   ((size_t)0)                        // 4*256*4096*8 = 33554432
#define WS_X2D   (WS_X1D + (size_t)33554432)        // 33554432
#define WS_W1TD  (WS_X2D + (size_t)33554432)        // 80*5*256*8   = 819200
#define WS_W2TD  (WS_W1TD + (size_t)819200)         // 256*5*256*8  = 2621440
#define WS_WDTD  (WS_W2TD + (size_t)2621440)        // 256*24*128*8 = 6291456
#define WS_A1D   (WS_WDTD + (size_t)6291456)        // 256*8 = 2048
#define WS_BT1D  (WS_A1D + 2048)
#define WS_A2D   (WS_BT1D + 2048)
#define WS_BT2D  (WS_A2D + 2048)
#define WS_WPD   (WS_BT2D + 2048)                   // 16*128*8 = 16384
#define WS_BPD   (WS_WPD + 16384)                   // 16*8 = 128
#define WS_ED    (WS_BPD + 128)                     // 16*128*341*8 = 5586944
#define WS_ZD    (WS_ED + (size_t)5586944)          // 16*341*16*8  = 698368
// total ~83.2 MB

// ---------------- prep: f64 transposes + BN fold ----------------
__global__ __launch_bounds__(256) void prep_f64(
    const float* __restrict__ w1, const float* __restrict__ w2,
    const float* __restrict__ wd,
    const float* __restrict__ b1, const float* __restrict__ g1,
    const float* __restrict__ be1, const float* __restrict__ m1,
    const float* __restrict__ v1,
    const float* __restrict__ b2, const float* __restrict__ g2,
    const float* __restrict__ be2, const float* __restrict__ m2,
    const float* __restrict__ v2,
    const float* __restrict__ wp, const float* __restrict__ bp,
    double* __restrict__ w1t, double* __restrict__ w2t, double* __restrict__ wdt,
    double* __restrict__ a1, double* __restrict__ bt1,
    double* __restrict__ a2, double* __restrict__ bt2,
    double* __restrict__ wpd, double* __restrict__ bpd)
{
    int j = blockIdx.x * 256 + threadIdx.x;
    if (j < 256*24*128) wdt[j] = (double)wd[(size_t)(j & 127) * 6144 + (j >> 7)];
    if (j < 256*5*256)  w2t[j] = (double)w2[(size_t)(j & 255) * 1280 + (j >> 8)];
    if (j < 80*5*256)   w1t[j] = (double)w1[(size_t)(j & 255) * 400 + (j >> 8)];
    if (j < 16*128)     wpd[j] = (double)wp[j];
    if (j < 16)         bpd[j] = (double)bp[j];
    if (j < 256) {
        double inv1 = 1.0 / sqrt((double)v1[j] + BN_EPS);
        double s1 = (double)g1[j] * inv1;
        a1[j]  = s1;
        bt1[j] = ((double)b1[j] - (double)m1[j]) * s1 + (double)be1[j];
        double inv2 = 1.0 / sqrt((double)v2[j] + BN_EPS);
        double s2 = (double)g2[j] * inv2;
        a2[j]  = s2;
        bt2[j] = ((double)b2[j] - (double)m2[j]) * s2 + (double)be2[j];
    }
}

// ---------------- f64 conv(k=5,pad=2) + BN + ReLU ----------------
// block: 64 co x 128 t for one (local) batch. 256 thr: 16 tcol (8 t) x 16 trow (4 co)
template<int CIN, typename Tin>
__global__ __launch_bounds__(256) void conv5_bn_relu_f64(
    const Tin* __restrict__ in,       // [BCH][CIN][T]
    const double* __restrict__ wt,    // [(ci*5+k)][256]
    const double* __restrict__ alpha, const double* __restrict__ beta,
    double* __restrict__ out)         // [BCH][256][T]
{
    const int b   = blockIdx.z;
    const int co0 = blockIdx.y * 64;
    const int t0  = blockIdx.x * 128;
    const int tid = threadIdx.x;
    const int tcol = tid & 15;
    const int trow = tid >> 4;

    __shared__ double xs[16][136];    // 17408 B
    __shared__ double wsh[80][64];    // 40960 B

    double acc[4][8];
    #pragma unroll
    for (int i = 0; i < 4; ++i)
        #pragma unroll
        for (int j = 0; j < 8; ++j) acc[i][j] = 0.0;

    for (int c0 = 0; c0 < CIN; c0 += 16) {
        for (int i = tid; i < 16 * 132; i += 256) {
            int ci = i / 132, col = i % 132;
            int t = t0 - 2 + col;
            double v = 0.0;
            if (t >= 0 && t < T_) v = (double)in[((size_t)(b * CIN + c0 + ci)) * T_ + t];
            xs[ci][col] = v;
        }
        for (int i = tid; i < 80 * 64; i += 256) {
            int r = i >> 6, co = i & 63;
            wsh[r][co] = wt[(size_t)(c0 * 5 + r) * 256 + co0 + co];
        }
        __syncthreads();

        for (int ci = 0; ci < 16; ++ci) {
            double xv[12];
            #pragma unroll
            for (int j = 0; j < 12; ++j) xv[j] = xs[ci][tcol * 8 + j];
            #pragma unroll
            for (int k = 0; k < 5; ++k) {
                double w0 = wsh[ci * 5 + k][trow * 4 + 0];
                double w1v = wsh[ci * 5 + k][trow * 4 + 1];
                double w2v = wsh[ci * 5 + k][trow * 4 + 2];
                double w3v = wsh[ci * 5 + k][trow * 4 + 3];
                #pragma unroll
                for (int j = 0; j < 8; ++j) {
                    double xq = xv[j + k];
                    acc[0][j] = fma(w0, xq, acc[0][j]);
                    acc[1][j] = fma(w1v, xq, acc[1][j]);
                    acc[2][j] = fma(w2v, xq, acc[2][j]);
                    acc[3][j] = fma(w3v, xq, acc[3][j]);
                }
            }
        }
        __syncthreads();
    }

    const int cobase = co0 + trow * 4;
    const int tg = t0 + tcol * 8;
    #pragma unroll
    for (int i = 0; i < 4; ++i) {
        double a = alpha[cobase + i], bt = beta[cobase + i];
        size_t base = ((size_t)(b * C_ + cobase + i)) * T_ + tg;
        #pragma unroll
        for (int j = 0; j < 8; ++j) {
            double y = fma(acc[i][j], a, bt);
            out[base + j] = y > 0.0 ? y : 0.0;
        }
    }
}

// ---------------- f64 downsample conv: k=24, stride=12, pad=6, + bias ----------------
// block: 64 co x 32 t'. 256 thr: 16 tcol (2 t') x 16 trow (4 co). ci-chunk 4.
__global__ __launch_bounds__(256) void convd_f64(
    const double* __restrict__ x2,    // [BCH][256][T]
    const double* __restrict__ wdt,   // [(ci*24+k)][128]
    const float* __restrict__ bd,     // [128]
    float* __restrict__ e_out,        // [BCH][128][341] (chunk base)
    double* __restrict__ ed)          // [BCH][128][341] (chunk base)
{
    const int b   = blockIdx.z;
    const int co0 = blockIdx.y * 64;
    const int tp0 = blockIdx.x * 32;
    const int tid = threadIdx.x;
    const int tcol = tid & 15;
    const int trow = tid >> 4;

    __shared__ double xs[4][400];     // 12800 B (span = 31*12+24 = 396)
    __shared__ double wsh[96][64];    // 49152 B

    double acc[4][2] = {{0.0,0.0},{0.0,0.0},{0.0,0.0},{0.0,0.0}};
    const int tbase = tp0 * 12 - 6;

    for (int c0 = 0; c0 < 256; c0 += 4) {
        for (int i = tid; i < 4 * 396; i += 256) {
            int ci = i / 396, col = i % 396;
            int t = tbase + col;
            xs[ci][col] = (t >= 0 && t < T_)
                ? x2[((size_t)(b * 256 + c0 + ci)) * T_ + t] : 0.0;
        }
        for (int i = tid; i < 96 * 64; i += 256) {
            int r = i >> 6, co = i & 63;
            wsh[r][co] = wdt[(size_t)(c0 * 24 + r) * 128 + co0 + co];
        }
        __syncthreads();

        for (int ci = 0; ci < 4; ++ci) {
            #pragma unroll 6
            for (int k = 0; k < 24; ++k) {
                double w0 = wsh[ci * 24 + k][trow * 4 + 0];
                double w1v = wsh[ci * 24 + k][trow * 4 + 1];
                double w2v = wsh[ci * 24 + k][trow * 4 + 2];
                double w3v = wsh[ci * 24 + k][trow * 4 + 3];
                double x0 = xs[ci][(tcol * 2 + 0) * 12 + k];
                double x1 = xs[ci][(tcol * 2 + 1) * 12 + k];
                acc[0][0] = fma(w0, x0, acc[0][0]);
                acc[0][1] = fma(w0, x1, acc[0][1]);
                acc[1][0] = fma(w1v, x0, acc[1][0]);
                acc[1][1] = fma(w1v, x1, acc[1][1]);
                acc[2][0] = fma(w2v, x0, acc[2][0]);
                acc[2][1] = fma(w2v, x1, acc[2][1]);
                acc[3][0] = fma(w3v, x0, acc[3][0]);
                acc[3][1] = fma(w3v, x1, acc[3][1]);
            }
        }
        __syncthreads();
    }

    #pragma unroll
    for (int i = 0; i < 4; ++i) {
        int co = co0 + trow * 4 + i;
        double bias = (double)bd[co];
        #pragma unroll
        for (int j = 0; j < 2; ++j) {
            int tp = tp0 + tcol * 2 + j;
            if (tp < TP) {
                double y = acc[i][j] + bias;
                size_t o = ((size_t)(b * EMB + co)) * TP + tp;
                e_out[o] = (float)y;
                ed[o] = y;
            }
        }
    }
}

// ---------------- f64 1x1 projection ----------------
__global__ __launch_bounds__(128) void zproj_f64(
    const double* __restrict__ ed,    // [B][128][341]
    const double* __restrict__ wpd,   // [16][128]
    const double* __restrict__ bpd,   // [16]
    double* __restrict__ z)           // [B][341][16]
{
    const int b = blockIdx.y;
    const int t = blockIdx.x * 128 + threadIdx.x;
    __shared__ double wps[16][128];
    for (int i = threadIdx.x; i < 16 * 128; i += 128)
        wps[i >> 7][i & 127] = wpd[i];
    __syncthreads();
    if (t >= TP) return;
    double acc[16];
    #pragma unroll
    for (int v = 0; v < 16; ++v) acc[v] = bpd[v];
    for (int co = 0; co < 128; ++co) {
        double x = ed[((size_t)(b * EMB + co)) * TP + t];
        #pragma unroll
        for (int v = 0; v < 16; ++v) acc[v] = fma(x, wps[v][co], acc[v]);
    }
    #pragma unroll
    for (int v = 0; v < 16; ++v)
        z[((size_t)(b * TP + t)) * 16 + v] = acc[v];
}

// ---------------- RVQ: f64 distances, f64 residual ----------------
__global__ __launch_bounds__(256) void rvq_f64(
    const double* __restrict__ z,     // [NPOS][16]
    const float* __restrict__ cb,     // [8][256][16]
    float* __restrict__ out_idx)      // [8][NPOS] as float
{
    const int pos = blockIdx.x;
    const int tid = threadIdx.x;
    __shared__ double r[16];
    __shared__ double dist_s[256];
    __shared__ int idx_s[256];

    if (tid < 16) r[tid] = z[(size_t)pos * 16 + tid];
    __syncthreads();

    for (int q = 0; q < NQ_; ++q) {
        const float* c = cb + ((size_t)(q * KCB) + tid) * 16;
        double d = 0.0;
        #pragma unroll
        for (int i = 0; i < 16; ++i) {
            double diff = r[i] - (double)c[i];
            d = fma(diff, diff, d);
        }
        dist_s[tid] = d;
        idx_s[tid] = tid;
        __syncthreads();
        for (int s = 128; s > 0; s >>= 1) {
            if (tid < s) {
                double d2 = dist_s[tid + s];
                int i2 = idx_s[tid + s];
                if (d2 < dist_s[tid] || (d2 == dist_s[tid] && i2 < idx_s[tid])) {
                    dist_s[tid] = d2;
                    idx_s[tid] = i2;
                }
            }
            __syncthreads();
        }
        int best = idx_s[0];
        if (tid < 16)
            r[tid] = r[tid] - (double)cb[((size_t)(q * KCB) + best) * 16 + tid];
        if (tid == 0)
            out_idx[(size_t)q * NPOS + pos] = (float)best;
        __syncthreads();
    }
}

// ---------------- host launcher ----------------
extern "C" void kernel_launch(void* const* d_in, const int* in_sizes, int n_in,
                              void* d_out, int out_size, void* d_ws, size_t ws_size,
                              hipStream_t stream) {
    const float* mel = (const float*)d_in[0];
    const float* w1  = (const float*)d_in[1];
    const float* b1  = (const float*)d_in[2];
    const float* g1  = (const float*)d_in[3];
    const float* be1 = (const float*)d_in[4];
    const float* m1  = (const float*)d_in[5];
    const float* v1  = (const float*)d_in[6];
    const float* w2  = (const float*)d_in[7];
    const float* b2  = (const float*)d_in[8];
    const float* g2  = (const float*)d_in[9];
    const float* be2 = (const float*)d_in[10];
    const float* m2  = (const float*)d_in[11];
    const float* v2  = (const float*)d_in[12];
    const float* wd  = (const float*)d_in[13];
    const float* bd  = (const float*)d_in[14];
    const float* wp  = (const float*)d_in[15];
    const float* bp  = (const float*)d_in[16];
    const float* cb  = (const float*)d_in[17];

    char* ws = (char*)d_ws;
    double* x1d  = (double*)(ws + WS_X1D);
    double* x2d  = (double*)(ws + WS_X2D);
    double* w1td = (double*)(ws + WS_W1TD);
    double* w2td = (double*)(ws + WS_W2TD);
    double* wdtd = (double*)(ws + WS_WDTD);
    double* a1d  = (double*)(ws + WS_A1D);
    double* bt1d = (double*)(ws + WS_BT1D);
    double* a2d  = (double*)(ws + WS_A2D);
    double* bt2d = (double*)(ws + WS_BT2D);
    double* wpd  = (double*)(ws + WS_WPD);
    double* bpd  = (double*)(ws + WS_BPD);
    double* ed   = (double*)(ws + WS_ED);
    double* zd   = (double*)(ws + WS_ZD);

    float* e_out   = (float*)d_out;                          // [16][128][341]
    float* idx_out = (float*)d_out + (size_t)B_ * EMB * TP;  // [8][16][341]

    prep_f64<<<3072, 256, 0, stream>>>(w1, w2, wd, b1, g1, be1, m1, v1,
                                       b2, g2, be2, m2, v2, wp, bp,
                                       w1td, w2td, wdtd, a1d, bt1d, a2d, bt2d,
                                       wpd, bpd);

    for (int ch = 0; ch < B_ / BCH; ++ch) {
        const float* mel_c = mel + (size_t)ch * BCH * CIN1 * T_;
        conv5_bn_relu_f64<CIN1, float><<<dim3(32, 4, BCH), 256, 0, stream>>>(
            mel_c, w1td, a1d, bt1d, x1d);
        conv5_bn_relu_f64<C_, double><<<dim3(32, 4, BCH), 256, 0, stream>>>(
            x1d, w2td, a2d, bt2d, x2d);
        convd_f64<<<dim3(11, 2, BCH), 256, 0, stream>>>(
            x2d, wdtd, bd,
            e_out + (size_t)ch * BCH * EMB * TP,
            ed + (size_t)ch * BCH * EMB * TP);
    }
    zproj_f64<<<dim3(3, 16), 128, 0, stream>>>(ed, wpd, bpd, zd);
    rvq_f64<<<NPOS, 256, 0, stream>>>(zd, cb, idx_out);
}

// Round 3
// 3173.773 us; speedup vs baseline: 1.3828x; 1.3828x over previous
//
#include <hip/hip_runtime.h>
#include <math.h>

#define B_    16
#define BCH   4            // batch chunk
#define T_    4096
#define C_    256
#define CIN1  80
#define EMB   128
#define STRIDE_ 12
#define TP    341
#define NPOS  (B_*TP)      // 5456
#define NQ_   8
#define KCB   256
#define BN_EPS 1e-5

// ---------------- workspace layout (bytes), all doubles ----------------
#define WS_X1D   ((size_t)0)                        // 4*256*4096*8 = 33554432
#define WS_X2D   (WS_X1D + (size_t)33554432)        // 33554432
#define WS_W1TD  (WS_X2D + (size_t)33554432)        // 80*5*256*8   = 819200
#define WS_W2TD  (WS_W1TD + (size_t)819200)         // 256*5*256*8  = 2621440
#define WS_WDTD  (WS_W2TD + (size_t)2621440)        // 256*24*128*8 = 6291456
#define WS_A1D   (WS_WDTD + (size_t)6291456)        // 256*8 = 2048
#define WS_BT1D  (WS_A1D + 2048)
#define WS_A2D   (WS_BT1D + 2048)
#define WS_BT2D  (WS_A2D + 2048)
#define WS_WPD   (WS_BT2D + 2048)                   // 16*128*8 = 16384
#define WS_BPD   (WS_WPD + 16384)                   // 128
#define WS_ED    (WS_BPD + 128)                     // 16*128*341*8 = 5586944
#define WS_ZD    (WS_ED + (size_t)5586944)          // 16*341*16*8  = 698368
// total ~83.2 MB

// ---------------- prep: f64 transposes + BN fold ----------------
__global__ __launch_bounds__(256) void prep_f64(
    const float* __restrict__ w1, const float* __restrict__ w2,
    const float* __restrict__ wd,
    const float* __restrict__ b1, const float* __restrict__ g1,
    const float* __restrict__ be1, const float* __restrict__ m1,
    const float* __restrict__ v1,
    const float* __restrict__ b2, const float* __restrict__ g2,
    const float* __restrict__ be2, const float* __restrict__ m2,
    const float* __restrict__ v2,
    const float* __restrict__ wp, const float* __restrict__ bp,
    double* __restrict__ w1t, double* __restrict__ w2t, double* __restrict__ wdt,
    double* __restrict__ a1, double* __restrict__ bt1,
    double* __restrict__ a2, double* __restrict__ bt2,
    double* __restrict__ wpd, double* __restrict__ bpd)
{
    int j = blockIdx.x * 256 + threadIdx.x;
    if (j < 256*24*128) wdt[j] = (double)wd[(size_t)(j & 127) * 6144 + (j >> 7)];
    if (j < 256*5*256)  w2t[j] = (double)w2[(size_t)(j & 255) * 1280 + (j >> 8)];
    if (j < 80*5*256)   w1t[j] = (double)w1[(size_t)(j & 255) * 400 + (j >> 8)];
    if (j < 16*128)     wpd[j] = (double)wp[j];
    if (j < 16)         bpd[j] = (double)bp[j];
    if (j < 256) {
        double inv1 = 1.0 / sqrt((double)v1[j] + BN_EPS);
        double s1 = (double)g1[j] * inv1;
        a1[j]  = s1;
        bt1[j] = ((double)b1[j] - (double)m1[j]) * s1 + (double)be1[j];
        double inv2 = 1.0 / sqrt((double)v2[j] + BN_EPS);
        double s2 = (double)g2[j] * inv2;
        a2[j]  = s2;
        bt2[j] = ((double)b2[j] - (double)m2[j]) * s2 + (double)be2[j];
    }
}

// ---------------- f64 conv(k=5,pad=2) + BN + ReLU ----------------
// block: 64 co x 128 t for one (local) batch. 256 thr: 16 tcol (8 t) x 16 trow (4 co)
template<int CIN, typename Tin>
__global__ __launch_bounds__(256) void conv5_bn_relu_f64(
    const Tin* __restrict__ in,       // [BCH][CIN][T]
    const double* __restrict__ wt,    // [(ci*5+k)][256]
    const double* __restrict__ alpha, const double* __restrict__ beta,
    double* __restrict__ out)         // [BCH][256][T]
{
    const int b   = blockIdx.z;
    const int co0 = blockIdx.y * 64;
    const int t0  = blockIdx.x * 128;
    const int tid = threadIdx.x;
    const int tcol = tid & 15;
    const int trow = tid >> 4;

    __shared__ double xs[16][136];    // 17408 B
    __shared__ double wsh[80][64];    // 40960 B

    double acc[4][8];
    #pragma unroll
    for (int i = 0; i < 4; ++i)
        #pragma unroll
        for (int j = 0; j < 8; ++j) acc[i][j] = 0.0;

    for (int c0 = 0; c0 < CIN; c0 += 16) {
        for (int i = tid; i < 16 * 132; i += 256) {
            int ci = i / 132, col = i % 132;
            int t = t0 - 2 + col;
            double v = 0.0;
            if (t >= 0 && t < T_) v = (double)in[((size_t)(b * CIN + c0 + ci)) * T_ + t];
            xs[ci][col] = v;
        }
        for (int i = tid; i < 80 * 64; i += 256) {
            int r = i >> 6, co = i & 63;
            wsh[r][co] = wt[(size_t)(c0 * 5 + r) * 256 + co0 + co];
        }
        __syncthreads();

        for (int ci = 0; ci < 16; ++ci) {
            double xv[12];
            #pragma unroll
            for (int j = 0; j < 12; ++j) xv[j] = xs[ci][tcol * 8 + j];
            #pragma unroll
            for (int k = 0; k < 5; ++k) {
                double w0 = wsh[ci * 5 + k][trow * 4 + 0];
                double w1v = wsh[ci * 5 + k][trow * 4 + 1];
                double w2v = wsh[ci * 5 + k][trow * 4 + 2];
                double w3v = wsh[ci * 5 + k][trow * 4 + 3];
                #pragma unroll
                for (int j = 0; j < 8; ++j) {
                    double xq = xv[j + k];
                    acc[0][j] = fma(w0, xq, acc[0][j]);
                    acc[1][j] = fma(w1v, xq, acc[1][j]);
                    acc[2][j] = fma(w2v, xq, acc[2][j]);
                    acc[3][j] = fma(w3v, xq, acc[3][j]);
                }
            }
        }
        __syncthreads();
    }

    const int cobase = co0 + trow * 4;
    const int tg = t0 + tcol * 8;
    #pragma unroll
    for (int i = 0; i < 4; ++i) {
        double a = alpha[cobase + i], bt = beta[cobase + i];
        size_t base = ((size_t)(b * C_ + cobase + i)) * T_ + tg;
        #pragma unroll
        for (int j = 0; j < 8; ++j) {
            double y = fma(acc[i][j], a, bt);
            out[base + j] = y > 0.0 ? y : 0.0;
        }
    }
}

// ---------------- f64 downsample conv v2: k=24, stride=12, pad=6, + bias ----------------
// block: 32 co x 32 t' for one local batch. 256 thr: tcol = tid&31 (1 t'),
// cog = tid>>5 (4 co each). ci-chunk 8.
__global__ __launch_bounds__(256) void convd_f64_v2(
    const double* __restrict__ x2,    // [BCH][256][T]
    const double* __restrict__ wdt,   // [(ci*24+k)][128]
    const float* __restrict__ bd,     // [128]
    float* __restrict__ e_out,        // [BCH][128][341] (chunk base)
    double* __restrict__ ed)          // [BCH][128][341] (chunk base)
{
    const int b   = blockIdx.z;
    const int co0 = blockIdx.y * 32;
    const int tp0 = blockIdx.x * 32;
    const int tid = threadIdx.x;
    const int tcol = tid & 31;
    const int cog  = tid >> 5;

    __shared__ double xs[8][396];     // 25344 B (span = 31*12+24 = 396)
    __shared__ double wsh[192][32];   // 49152 B

    double acc[4] = {0.0, 0.0, 0.0, 0.0};
    const int tbase = tp0 * 12 - 6;

    for (int c0 = 0; c0 < 256; c0 += 8) {
        for (int i = tid; i < 8 * 396; i += 256) {
            int ci = i / 396, col = i % 396;
            int t = tbase + col;
            xs[ci][col] = (t >= 0 && t < T_)
                ? x2[((size_t)(b * 256 + c0 + ci)) * T_ + t] : 0.0;
        }
        for (int i = tid; i < 192 * 32; i += 256) {
            int r = i >> 5, c = i & 31;
            wsh[r][c] = wdt[(size_t)(c0 * 24 + r) * 128 + co0 + c];
        }
        __syncthreads();

        #pragma unroll 2
        for (int ci = 0; ci < 8; ++ci) {
            #pragma unroll
            for (int k = 0; k < 24; k += 2) {
                double2 xp = *(const double2*)&xs[ci][tcol * 12 + k];
                const double* wr0 = &wsh[ci * 24 + k][cog * 4];
                const double* wr1 = &wsh[ci * 24 + k + 1][cog * 4];
                #pragma unroll
                for (int i = 0; i < 4; ++i) acc[i] = fma(wr0[i], xp.x, acc[i]);
                #pragma unroll
                for (int i = 0; i < 4; ++i) acc[i] = fma(wr1[i], xp.y, acc[i]);
            }
        }
        __syncthreads();
    }

    const int tp = tp0 + tcol;
    if (tp < TP) {
        #pragma unroll
        for (int i = 0; i < 4; ++i) {
            int co = co0 + cog * 4 + i;
            double y = acc[i] + (double)bd[co];
            size_t o = ((size_t)(b * EMB + co)) * TP + tp;
            e_out[o] = (float)y;
            ed[o] = y;
        }
    }
}

// ---------------- f64 1x1 projection ----------------
__global__ __launch_bounds__(128) void zproj_f64(
    const double* __restrict__ ed,    // [B][128][341]
    const double* __restrict__ wpd,   // [16][128]
    const double* __restrict__ bpd,   // [16]
    double* __restrict__ z)           // [B][341][16]
{
    const int b = blockIdx.y;
    const int t = blockIdx.x * 128 + threadIdx.x;
    __shared__ double wps[16][128];
    for (int i = threadIdx.x; i < 16 * 128; i += 128)
        wps[i >> 7][i & 127] = wpd[i];
    __syncthreads();
    if (t >= TP) return;
    double acc[16];
    #pragma unroll
    for (int v = 0; v < 16; ++v) acc[v] = bpd[v];
    for (int co = 0; co < 128; ++co) {
        double x = ed[((size_t)(b * EMB + co)) * TP + t];
        #pragma unroll
        for (int v = 0; v < 16; ++v) acc[v] = fma(x, wps[v][co], acc[v]);
    }
    #pragma unroll
    for (int v = 0; v < 16; ++v)
        z[((size_t)(b * TP + t)) * 16 + v] = acc[v];
}

// ---------------- RVQ: f64 distances, wave-shuffle argmin ----------------
__global__ __launch_bounds__(256) void rvq_f64_v2(
    const double* __restrict__ z,     // [NPOS][16]
    const float* __restrict__ cb,     // [8][256][16]
    float* __restrict__ out_idx)      // [8][NPOS] as float
{
    const int pos = blockIdx.x;
    const int tid = threadIdx.x;
    const int lane = tid & 63;
    const int wv = tid >> 6;

    __shared__ double r[16];
    __shared__ double wd_s[4];
    __shared__ int wi_s[4];
    __shared__ int best_s;

    if (tid < 16) r[tid] = z[(size_t)pos * 16 + tid];
    __syncthreads();

    for (int q = 0; q < NQ_; ++q) {
        const float* c = cb + ((size_t)(q * KCB) + tid) * 16;
        double d = 0.0;
        #pragma unroll
        for (int i = 0; i < 16; ++i) {
            double diff = r[i] - (double)c[i];
            d = fma(diff, diff, d);
        }
        int idx = tid;
        // wave-level argmin (first-min tie-break preserved by i2<idx)
        #pragma unroll
        for (int s = 32; s > 0; s >>= 1) {
            double d2 = __shfl_down(d, s, 64);
            int i2 = __shfl_down(idx, s, 64);
            if (d2 < d || (d2 == d && i2 < idx)) { d = d2; idx = i2; }
        }
        if (lane == 0) { wd_s[wv] = d; wi_s[wv] = idx; }
        __syncthreads();
        if (tid == 0) {
            double bd_ = wd_s[0]; int bi = wi_s[0];
            #pragma unroll
            for (int w = 1; w < 4; ++w) {
                if (wd_s[w] < bd_ || (wd_s[w] == bd_ && wi_s[w] < bi)) {
                    bd_ = wd_s[w]; bi = wi_s[w];
                }
            }
            best_s = bi;
            out_idx[(size_t)q * NPOS + pos] = (float)bi;
        }
        __syncthreads();
        int best = best_s;
        if (tid < 16)
            r[tid] = r[tid] - (double)cb[((size_t)(q * KCB) + best) * 16 + tid];
        __syncthreads();
    }
}

// ---------------- host launcher ----------------
extern "C" void kernel_launch(void* const* d_in, const int* in_sizes, int n_in,
                              void* d_out, int out_size, void* d_ws, size_t ws_size,
                              hipStream_t stream) {
    const float* mel = (const float*)d_in[0];
    const float* w1  = (const float*)d_in[1];
    const float* b1  = (const float*)d_in[2];
    const float* g1  = (const float*)d_in[3];
    const float* be1 = (const float*)d_in[4];
    const float* m1  = (const float*)d_in[5];
    const float* v1  = (const float*)d_in[6];
    const float* w2  = (const float*)d_in[7];
    const float* b2  = (const float*)d_in[8];
    const float* g2  = (const float*)d_in[9];
    const float* be2 = (const float*)d_in[10];
    const float* m2  = (const float*)d_in[11];
    const float* v2  = (const float*)d_in[12];
    const float* wd  = (const float*)d_in[13];
    const float* bd  = (const float*)d_in[14];
    const float* wp  = (const float*)d_in[15];
    const float* bp  = (const float*)d_in[16];
    const float* cb  = (const float*)d_in[17];

    char* ws = (char*)d_ws;
    double* x1d  = (double*)(ws + WS_X1D);
    double* x2d  = (double*)(ws + WS_X2D);
    double* w1td = (double*)(ws + WS_W1TD);
    double* w2td = (double*)(ws + WS_W2TD);
    double* wdtd = (double*)(ws + WS_WDTD);
    double* a1d  = (double*)(ws + WS_A1D);
    double* bt1d = (double*)(ws + WS_BT1D);
    double* a2d  = (double*)(ws + WS_A2D);
    double* bt2d = (double*)(ws + WS_BT2D);
    double* wpd  = (double*)(ws + WS_WPD);
    double* bpd  = (double*)(ws + WS_BPD);
    double* ed   = (double*)(ws + WS_ED);
    double* zd   = (double*)(ws + WS_ZD);

    float* e_out   = (float*)d_out;                          // [16][128][341]
    float* idx_out = (float*)d_out + (size_t)B_ * EMB * TP;  // [8][16][341]

    prep_f64<<<3072, 256, 0, stream>>>(w1, w2, wd, b1, g1, be1, m1, v1,
                                       b2, g2, be2, m2, v2, wp, bp,
                                       w1td, w2td, wdtd, a1d, bt1d, a2d, bt2d,
                                       wpd, bpd);

    for (int ch = 0; ch < B_ / BCH; ++ch) {
        const float* mel_c = mel + (size_t)ch * BCH * CIN1 * T_;
        conv5_bn_relu_f64<CIN1, float><<<dim3(32, 4, BCH), 256, 0, stream>>>(
            mel_c, w1td, a1d, bt1d, x1d);
        conv5_bn_relu_f64<C_, double><<<dim3(32, 4, BCH), 256, 0, stream>>>(
            x1d, w2td, a2d, bt2d, x2d);
        convd_f64_v2<<<dim3(11, 4, BCH), 256, 0, stream>>>(
            x2d, wdtd, bd,
            e_out + (size_t)ch * BCH * EMB * TP,
            ed + (size_t)ch * BCH * EMB * TP);
    }
    zproj_f64<<<dim3(3, 16), 128, 0, stream>>>(ed, wpd, bpd, zd);
    rvq_f64_v2<<<NPOS, 256, 0, stream>>>(zd, cb, idx_out);
}

// Round 4
// 1865.604 us; speedup vs baseline: 2.3525x; 1.7012x over previous
//
#include <hip/hip_runtime.h>
#include <math.h>

#define B_    16
#define BCH   4            // batch chunk for conv1/conv2
#define T_    4096
#define C_    256
#define CIN1  80
#define EMB   128
#define TP    341
#define NPOS  (B_*TP)      // 5456
#define NQ_   8
#define KCB   256
#define BN_EPS 1e-5

// ---------------- prep: f64 transposes + BN fold ----------------
__global__ __launch_bounds__(256) void prep_f64(
    const float* __restrict__ w1, const float* __restrict__ w2,
    const float* __restrict__ wd,
    const float* __restrict__ b1, const float* __restrict__ g1,
    const float* __restrict__ be1, const float* __restrict__ m1,
    const float* __restrict__ v1,
    const float* __restrict__ b2, const float* __restrict__ g2,
    const float* __restrict__ be2, const float* __restrict__ m2,
    const float* __restrict__ v2,
    const float* __restrict__ wp, const float* __restrict__ bp,
    double* __restrict__ w1t, double* __restrict__ w2t, double* __restrict__ wdt,
    double* __restrict__ a1, double* __restrict__ bt1,
    double* __restrict__ a2, double* __restrict__ bt2,
    double* __restrict__ wpd, double* __restrict__ bpd)
{
    int j = blockIdx.x * 256 + threadIdx.x;
    if (j < 256*24*128) wdt[j] = (double)wd[(size_t)(j & 127) * 6144 + (j >> 7)];
    if (j < 256*5*256)  w2t[j] = (double)w2[(size_t)(j & 255) * 1280 + (j >> 8)];
    if (j < 80*5*256)   w1t[j] = (double)w1[(size_t)(j & 255) * 400 + (j >> 8)];
    if (j < 16*128)     wpd[j] = (double)wp[j];
    if (j < 16)         bpd[j] = (double)bp[j];
    if (j < 256) {
        double inv1 = 1.0 / sqrt((double)v1[j] + BN_EPS);
        double s1 = (double)g1[j] * inv1;
        a1[j]  = s1;
        bt1[j] = ((double)b1[j] - (double)m1[j]) * s1 + (double)be1[j];
        double inv2 = 1.0 / sqrt((double)v2[j] + BN_EPS);
        double s2 = (double)g2[j] * inv2;
        a2[j]  = s2;
        bt2[j] = ((double)b2[j] - (double)m2[j]) * s2 + (double)be2[j];
    }
}

// ---------------- f64 conv(k=5,pad=2) + BN + ReLU ----------------
// block: 64 co x 128 t for one (local) batch. 256 thr: 16 tcol (8 t) x 16 trow (4 co)
template<int CIN, typename Tin>
__global__ __launch_bounds__(256) void conv5_bn_relu_f64(
    const Tin* __restrict__ in,       // [BCH][CIN][T]
    const double* __restrict__ wt,    // [(ci*5+k)][256]
    const double* __restrict__ alpha, const double* __restrict__ beta,
    double* __restrict__ out)         // [BCH][256][T]
{
    const int b   = blockIdx.z;
    const int co0 = blockIdx.y * 64;
    const int t0  = blockIdx.x * 128;
    const int tid = threadIdx.x;
    const int tcol = tid & 15;
    const int trow = tid >> 4;

    __shared__ double xs[16][136];    // 17408 B
    __shared__ double wsh[80][64];    // 40960 B

    double acc[4][8];
    #pragma unroll
    for (int i = 0; i < 4; ++i)
        #pragma unroll
        for (int j = 0; j < 8; ++j) acc[i][j] = 0.0;

    for (int c0 = 0; c0 < CIN; c0 += 16) {
        for (int i = tid; i < 16 * 132; i += 256) {
            int ci = i / 132, col = i % 132;
            int t = t0 - 2 + col;
            double v = 0.0;
            if (t >= 0 && t < T_) v = (double)in[((size_t)(b * CIN + c0 + ci)) * T_ + t];
            xs[ci][col] = v;
        }
        for (int i = tid; i < 80 * 64; i += 256) {
            int r = i >> 6, co = i & 63;
            wsh[r][co] = wt[(size_t)(c0 * 5 + r) * 256 + co0 + co];
        }
        __syncthreads();

        for (int ci = 0; ci < 16; ++ci) {
            double xv[12];
            #pragma unroll
            for (int j = 0; j < 12; ++j) xv[j] = xs[ci][tcol * 8 + j];
            #pragma unroll
            for (int k = 0; k < 5; ++k) {
                double w0 = wsh[ci * 5 + k][trow * 4 + 0];
                double w1v = wsh[ci * 5 + k][trow * 4 + 1];
                double w2v = wsh[ci * 5 + k][trow * 4 + 2];
                double w3v = wsh[ci * 5 + k][trow * 4 + 3];
                #pragma unroll
                for (int j = 0; j < 8; ++j) {
                    double xq = xv[j + k];
                    acc[0][j] = fma(w0, xq, acc[0][j]);
                    acc[1][j] = fma(w1v, xq, acc[1][j]);
                    acc[2][j] = fma(w2v, xq, acc[2][j]);
                    acc[3][j] = fma(w3v, xq, acc[3][j]);
                }
            }
        }
        __syncthreads();
    }

    const int cobase = co0 + trow * 4;
    const int tg = t0 + tcol * 8;
    #pragma unroll
    for (int i = 0; i < 4; ++i) {
        double a = alpha[cobase + i], bt = beta[cobase + i];
        size_t base = ((size_t)(b * C_ + cobase + i)) * T_ + tg;
        #pragma unroll
        for (int j = 0; j < 8; ++j) {
            double y = fma(acc[i][j], a, bt);
            out[base + j] = y > 0.0 ? y : 0.0;
        }
    }
}

// ---------------- f64 downsample conv v4: k=24, stride=12, pad=6 ----------------
// One launch over nb batches. block: 64 co x 64 tp; 256 thr: tcol=tid&15 (4 tp),
// crow=tid>>4 (4 co). grid: (6 tp-tiles, 2 co-tiles, nb*4 ci-splits).
// Each block reduces 64 ci (split s covers ci [s*64, s*64+64)), writes f64 partial.
__global__ __launch_bounds__(256) void convd_f64_v4(
    const double* __restrict__ x2,    // [nb][256][T]
    const double* __restrict__ wdt,   // [(ci*24+k)][128]
    double* __restrict__ parts,       // [4][nb][128][341]
    int nb)
{
    const int bz  = blockIdx.z;
    const int s   = bz & 3;
    const int b   = bz >> 2;
    const int co0 = blockIdx.y * 64;
    const int tp0 = blockIdx.x * 64;
    const int tid = threadIdx.x;
    const int tcol = tid & 15;
    const int crow = tid >> 4;
    const int ci0 = s * 64;

    __shared__ double xs[2][780];     // 12480 B (span = 63*12+23+1 = 780)
    __shared__ double wsh[48][64];    // 24576 B

    double acc[4][4];
    #pragma unroll
    for (int i = 0; i < 4; ++i)
        #pragma unroll
        for (int j = 0; j < 4; ++j) acc[i][j] = 0.0;

    const int tbase = tp0 * 12 - 6;

    for (int c0 = ci0; c0 < ci0 + 64; c0 += 2) {
        for (int i = tid; i < 2 * 780; i += 256) {
            int ci = i / 780, col = i % 780;
            int t = tbase + col;
            xs[ci][col] = (t >= 0 && t < T_)
                ? x2[((size_t)(b * 256 + c0 + ci)) * T_ + t] : 0.0;
        }
        for (int i = tid; i < 48 * 64; i += 256) {
            int r = i >> 6, c = i & 63;
            // (c0 + r/24)*24 + r%24 == c0*24 + r
            wsh[r][c] = wdt[(size_t)(c0 * 24 + r) * 128 + co0 + c];
        }
        __syncthreads();

        #pragma unroll
        for (int ci = 0; ci < 2; ++ci) {
            #pragma unroll
            for (int k = 0; k < 24; k += 2) {
                double2 wa0 = *(const double2*)&wsh[ci * 24 + k][crow * 4];
                double2 wa1 = *(const double2*)&wsh[ci * 24 + k][crow * 4 + 2];
                double2 wb0 = *(const double2*)&wsh[ci * 24 + k + 1][crow * 4];
                double2 wb1 = *(const double2*)&wsh[ci * 24 + k + 1][crow * 4 + 2];
                #pragma unroll
                for (int j = 0; j < 4; ++j) {
                    double2 xp = *(const double2*)&xs[ci][(tcol * 4 + j) * 12 + k];
                    acc[0][j] = fma(wa0.x, xp.x, acc[0][j]);
                    acc[1][j] = fma(wa0.y, xp.x, acc[1][j]);
                    acc[2][j] = fma(wa1.x, xp.x, acc[2][j]);
                    acc[3][j] = fma(wa1.y, xp.x, acc[3][j]);
                    acc[0][j] = fma(wb0.x, xp.y, acc[0][j]);
                    acc[1][j] = fma(wb0.y, xp.y, acc[1][j]);
                    acc[2][j] = fma(wb1.x, xp.y, acc[2][j]);
                    acc[3][j] = fma(wb1.y, xp.y, acc[3][j]);
                }
            }
        }
        __syncthreads();
    }

    #pragma unroll
    for (int i = 0; i < 4; ++i) {
        int co = co0 + crow * 4 + i;
        #pragma unroll
        for (int j = 0; j < 4; ++j) {
            int tp = tp0 + tcol * 4 + j;
            if (tp < TP)
                parts[(((size_t)s * nb + b) * EMB + co) * TP + tp] = acc[i][j];
        }
    }
}

// ---------------- combine partials + bias -> ed (f64) + e_out (f32) ----------------
__global__ __launch_bounds__(256) void convd_combine(
    const double* __restrict__ parts, // [4][nb][128][341]
    const float* __restrict__ bd,
    double* __restrict__ ed,          // [16][128][341] (absolute b)
    float* __restrict__ e_out,        // [16][128][341]
    int nb, int b_off)
{
    int idx = blockIdx.x * 256 + threadIdx.x;
    int total = nb * EMB * TP;
    if (idx >= total) return;
    int b_local = idx / (EMB * TP);
    int rem = idx % (EMB * TP);
    int co = rem / TP;
    size_t stride = (size_t)nb * EMB * TP;
    double y = parts[idx];
    y += parts[stride + idx];
    y += parts[2 * stride + idx];
    y += parts[3 * stride + idx];
    y += (double)bd[co];
    size_t o = (size_t)(b_off + b_local) * EMB * TP + rem;
    ed[o] = y;
    e_out[o] = (float)y;
}

// ---------------- f64 1x1 projection ----------------
__global__ __launch_bounds__(128) void zproj_f64(
    const double* __restrict__ ed,    // [B][128][341]
    const double* __restrict__ wpd,   // [16][128]
    const double* __restrict__ bpd,   // [16]
    double* __restrict__ z)           // [B][341][16]
{
    const int b = blockIdx.y;
    const int t = blockIdx.x * 128 + threadIdx.x;
    __shared__ double wps[16][128];
    for (int i = threadIdx.x; i < 16 * 128; i += 128)
        wps[i >> 7][i & 127] = wpd[i];
    __syncthreads();
    if (t >= TP) return;
    double acc[16];
    #pragma unroll
    for (int v = 0; v < 16; ++v) acc[v] = bpd[v];
    for (int co = 0; co < 128; ++co) {
        double x = ed[((size_t)(b * EMB + co)) * TP + t];
        #pragma unroll
        for (int v = 0; v < 16; ++v) acc[v] = fma(x, wps[v][co], acc[v]);
    }
    #pragma unroll
    for (int v = 0; v < 16; ++v)
        z[((size_t)(b * TP + t)) * 16 + v] = acc[v];
}

// ---------------- RVQ: f64 distances, wave-shuffle argmin ----------------
__global__ __launch_bounds__(256) void rvq_f64_v2(
    const double* __restrict__ z,     // [NPOS][16]
    const float* __restrict__ cb,     // [8][256][16]
    float* __restrict__ out_idx)      // [8][NPOS] as float
{
    const int pos = blockIdx.x;
    const int tid = threadIdx.x;
    const int lane = tid & 63;
    const int wv = tid >> 6;

    __shared__ double r[16];
    __shared__ double wd_s[4];
    __shared__ int wi_s[4];
    __shared__ int best_s;

    if (tid < 16) r[tid] = z[(size_t)pos * 16 + tid];
    __syncthreads();

    for (int q = 0; q < NQ_; ++q) {
        const float* c = cb + ((size_t)(q * KCB) + tid) * 16;
        double d = 0.0;
        #pragma unroll
        for (int i = 0; i < 16; ++i) {
            double diff = r[i] - (double)c[i];
            d = fma(diff, diff, d);
        }
        int idx = tid;
        #pragma unroll
        for (int sft = 32; sft > 0; sft >>= 1) {
            double d2 = __shfl_down(d, sft, 64);
            int i2 = __shfl_down(idx, sft, 64);
            if (d2 < d || (d2 == d && i2 < idx)) { d = d2; idx = i2; }
        }
        if (lane == 0) { wd_s[wv] = d; wi_s[wv] = idx; }
        __syncthreads();
        if (tid == 0) {
            double bd_ = wd_s[0]; int bi = wi_s[0];
            #pragma unroll
            for (int w = 1; w < 4; ++w) {
                if (wd_s[w] < bd_ || (wd_s[w] == bd_ && wi_s[w] < bi)) {
                    bd_ = wd_s[w]; bi = wi_s[w];
                }
            }
            best_s = bi;
            out_idx[(size_t)q * NPOS + pos] = (float)bi;
        }
        __syncthreads();
        int best = best_s;
        if (tid < 16)
            r[tid] = r[tid] - (double)cb[((size_t)(q * KCB) + best) * 16 + tid];
        __syncthreads();
    }
}

// ---------------- host launcher ----------------
extern "C" void kernel_launch(void* const* d_in, const int* in_sizes, int n_in,
                              void* d_out, int out_size, void* d_ws, size_t ws_size,
                              hipStream_t stream) {
    const float* mel = (const float*)d_in[0];
    const float* w1  = (const float*)d_in[1];
    const float* b1  = (const float*)d_in[2];
    const float* g1  = (const float*)d_in[3];
    const float* be1 = (const float*)d_in[4];
    const float* m1  = (const float*)d_in[5];
    const float* v1  = (const float*)d_in[6];
    const float* w2  = (const float*)d_in[7];
    const float* b2  = (const float*)d_in[8];
    const float* g2  = (const float*)d_in[9];
    const float* be2 = (const float*)d_in[10];
    const float* m2  = (const float*)d_in[11];
    const float* v2  = (const float*)d_in[12];
    const float* wd  = (const float*)d_in[13];
    const float* bd  = (const float*)d_in[14];
    const float* wp  = (const float*)d_in[15];
    const float* bp  = (const float*)d_in[16];
    const float* cb  = (const float*)d_in[17];

    // pick nb (batches covered by one convd launch) based on ws_size
    // need(nb) = x1(33.55M) + x2(nb*8.39M) + weights(9.73M) + scalars
    //            + ed(5.59M) + zd(0.70M) + parts(4*nb*0.349M)
    auto need = [](int nb) -> size_t {
        size_t s = 0;
        s += (size_t)BCH * C_ * T_ * 8;                 // x1
        s += (size_t)nb * C_ * T_ * 8;                  // x2
        s += (size_t)80*5*256*8 + (size_t)256*5*256*8 + (size_t)256*24*128*8;
        s += 6 * 4096;                                  // scalars w/ padding slack
        s += (size_t)16 * EMB * TP * 8;                 // ed
        s += (size_t)16 * TP * 16 * 8;                  // zd
        s += (size_t)4 * nb * EMB * TP * 8;             // parts
        s += 64 * 1024;                                 // alignment slack
        return s;
    };
    const int nb = (ws_size >= need(16)) ? 16 : 8;
    const int ngrp = B_ / nb;

    char* ws = (char*)d_ws;
    size_t off = 0;
    auto alloc = [&](size_t bytes) -> char* {
        char* p = ws + off;
        off = (off + bytes + 255) & ~(size_t)255;
        return p;
    };
    double* x1d  = (double*)alloc((size_t)BCH * C_ * T_ * 8);
    double* x2d  = (double*)alloc((size_t)nb * C_ * T_ * 8);
    double* w1td = (double*)alloc((size_t)80*5*256*8);
    double* w2td = (double*)alloc((size_t)256*5*256*8);
    double* wdtd = (double*)alloc((size_t)256*24*128*8);
    double* a1d  = (double*)alloc(2048);
    double* bt1d = (double*)alloc(2048);
    double* a2d  = (double*)alloc(2048);
    double* bt2d = (double*)alloc(2048);
    double* wpd  = (double*)alloc(16*128*8);
    double* bpd  = (double*)alloc(16*8);
    double* ed   = (double*)alloc((size_t)16 * EMB * TP * 8);
    double* zd   = (double*)alloc((size_t)16 * TP * 16 * 8);
    double* parts= (double*)alloc((size_t)4 * nb * EMB * TP * 8);

    float* e_out   = (float*)d_out;                          // [16][128][341]
    float* idx_out = (float*)d_out + (size_t)B_ * EMB * TP;  // [8][16][341]

    prep_f64<<<3072, 256, 0, stream>>>(w1, w2, wd, b1, g1, be1, m1, v1,
                                       b2, g2, be2, m2, v2, wp, bp,
                                       w1td, w2td, wdtd, a1d, bt1d, a2d, bt2d,
                                       wpd, bpd);

    const int comb_blocks = (nb * EMB * TP + 255) / 256;
    for (int g = 0; g < ngrp; ++g) {
        for (int ch = 0; ch < nb / BCH; ++ch) {
            int ch_abs = g * (nb / BCH) + ch;
            const float* mel_c = mel + (size_t)ch_abs * BCH * CIN1 * T_;
            conv5_bn_relu_f64<CIN1, float><<<dim3(32, 4, BCH), 256, 0, stream>>>(
                mel_c, w1td, a1d, bt1d, x1d);
            conv5_bn_relu_f64<C_, double><<<dim3(32, 4, BCH), 256, 0, stream>>>(
                x1d, w2td, a2d, bt2d, x2d + (size_t)ch * BCH * C_ * T_);
        }
        convd_f64_v4<<<dim3(6, 2, nb * 4), 256, 0, stream>>>(x2d, wdtd, parts, nb);
        convd_combine<<<comb_blocks, 256, 0, stream>>>(parts, bd, ed, e_out,
                                                       nb, g * nb);
    }
    zproj_f64<<<dim3(3, 16), 128, 0, stream>>>(ed, wpd, bpd, zd);
    rvq_f64_v2<<<NPOS, 256, 0, stream>>>(zd, cb, idx_out);
}

// Round 5
// 1662.120 us; speedup vs baseline: 2.6405x; 1.1224x over previous
//
#include <hip/hip_runtime.h>
#include <math.h>

#define B_    16
#define BCH   4            // batch chunk for conv1/conv2
#define T_    4096
#define C_    256
#define CIN1  80
#define EMB   128
#define TP    341
#define NPOS  (B_*TP)      // 5456
#define NQ_   8
#define KCB   256
#define BN_EPS 1e-5

// ---------------- prep: f64 transposes + BN fold ----------------
__global__ __launch_bounds__(256) void prep_f64(
    const float* __restrict__ w1, const float* __restrict__ w2,
    const float* __restrict__ wd,
    const float* __restrict__ b1, const float* __restrict__ g1,
    const float* __restrict__ be1, const float* __restrict__ m1,
    const float* __restrict__ v1,
    const float* __restrict__ b2, const float* __restrict__ g2,
    const float* __restrict__ be2, const float* __restrict__ m2,
    const float* __restrict__ v2,
    const float* __restrict__ wp, const float* __restrict__ bp,
    double* __restrict__ w1t, double* __restrict__ w2t, double* __restrict__ wdt,
    double* __restrict__ a1, double* __restrict__ bt1,
    double* __restrict__ a2, double* __restrict__ bt2,
    double* __restrict__ wpd, double* __restrict__ bpd)
{
    int j = blockIdx.x * 256 + threadIdx.x;
    if (j < 256*24*128) wdt[j] = (double)wd[(size_t)(j & 127) * 6144 + (j >> 7)];
    if (j < 256*5*256)  w2t[j] = (double)w2[(size_t)(j & 255) * 1280 + (j >> 8)];
    if (j < 80*5*256)   w1t[j] = (double)w1[(size_t)(j & 255) * 400 + (j >> 8)];
    if (j < 16*128)     wpd[j] = (double)wp[j];
    if (j < 16)         bpd[j] = (double)bp[j];
    if (j < 256) {
        double inv1 = 1.0 / sqrt((double)v1[j] + BN_EPS);
        double s1 = (double)g1[j] * inv1;
        a1[j]  = s1;
        bt1[j] = ((double)b1[j] - (double)m1[j]) * s1 + (double)be1[j];
        double inv2 = 1.0 / sqrt((double)v2[j] + BN_EPS);
        double s2 = (double)g2[j] * inv2;
        a2[j]  = s2;
        bt2[j] = ((double)b2[j] - (double)m2[j]) * s2 + (double)be2[j];
    }
}

// bank swizzle on 16B granularity: permutes within aligned 8-block (128B) groups
__device__ __forceinline__ int swz_pair(int col) {        // col even, 16B unit
    int bw = col >> 1;
    return ((bw ^ ((bw >> 3) & 7)) << 1);
}
__device__ __forceinline__ int swz_scalar(int col) {      // any col (8B unit)
    int bw = col >> 1;
    return (((bw ^ ((bw >> 3) & 7)) << 1) | (col & 1));
}

// ---------------- f64 conv(k=5,pad=2) + BN + ReLU ----------------
// block: 64 co x 128 t for one (local) batch. 256 thr: 16 tcol (8 t) x 16 trow (4 co)
// 8-ci chunks -> 29 KB LDS -> 5 blocks/CU. Swizzled x-tile.
template<int CIN, typename Tin>
__global__ __launch_bounds__(256) void conv5_bn_relu_f64(
    const Tin* __restrict__ in,       // [BCH][CIN][T]
    const double* __restrict__ wt,    // [(ci*5+k)][256]
    const double* __restrict__ alpha, const double* __restrict__ beta,
    double* __restrict__ out)         // [BCH][256][T]
{
    const int b   = blockIdx.z;
    const int co0 = blockIdx.y * 64;
    const int t0  = blockIdx.x * 128;
    const int tid = threadIdx.x;
    const int tcol = tid & 15;
    const int trow = tid >> 4;

    __shared__ double xs[8][136];     // 8704 B (132 used, swizzled)
    __shared__ double wsh[40][64];    // 20480 B

    double acc[4][8];
    #pragma unroll
    for (int i = 0; i < 4; ++i)
        #pragma unroll
        for (int j = 0; j < 8; ++j) acc[i][j] = 0.0;

    for (int c0 = 0; c0 < CIN; c0 += 8) {
        for (int i = tid; i < 8 * 132; i += 256) {
            int ci = i / 132, col = i % 132;
            int t = t0 - 2 + col;
            double v = 0.0;
            if (t >= 0 && t < T_) v = (double)in[((size_t)(b * CIN + c0 + ci)) * T_ + t];
            xs[ci][swz_scalar(col)] = v;
        }
        for (int i = tid; i < 40 * 64; i += 256) {
            int r = i >> 6, co = i & 63;
            wsh[r][co] = wt[(size_t)(c0 * 5 + r) * 256 + co0 + co];
        }
        __syncthreads();

        #pragma unroll
        for (int ci = 0; ci < 8; ++ci) {
            double xv[12];
            #pragma unroll
            for (int m = 0; m < 6; ++m) {
                double2 v = *(const double2*)&xs[ci][swz_pair(tcol * 8 + 2 * m)];
                xv[2 * m] = v.x; xv[2 * m + 1] = v.y;
            }
            #pragma unroll
            for (int k = 0; k < 5; ++k) {
                double w0 = wsh[ci * 5 + k][trow * 4 + 0];
                double w1v = wsh[ci * 5 + k][trow * 4 + 1];
                double w2v = wsh[ci * 5 + k][trow * 4 + 2];
                double w3v = wsh[ci * 5 + k][trow * 4 + 3];
                #pragma unroll
                for (int j = 0; j < 8; ++j) {
                    double xq = xv[j + k];
                    acc[0][j] = fma(w0, xq, acc[0][j]);
                    acc[1][j] = fma(w1v, xq, acc[1][j]);
                    acc[2][j] = fma(w2v, xq, acc[2][j]);
                    acc[3][j] = fma(w3v, xq, acc[3][j]);
                }
            }
        }
        __syncthreads();
    }

    const int cobase = co0 + trow * 4;
    const int tg = t0 + tcol * 8;
    #pragma unroll
    for (int i = 0; i < 4; ++i) {
        double a = alpha[cobase + i], bt = beta[cobase + i];
        size_t base = ((size_t)(b * C_ + cobase + i)) * T_ + tg;
        #pragma unroll
        for (int j = 0; j < 8; ++j) {
            double y = fma(acc[i][j], a, bt);
            out[base + j] = y > 0.0 ? y : 0.0;
        }
    }
}

// ---------------- f64 downsample conv v5: k=24, stride=12, pad=6 ----------------
// All nb batches, ci split nsplit ways. block: 64 co x 128 tp; 256 thr:
// crow=tid>>5 (8 co each), tcol=tid&31, tp = tp0 + tcol + 32j (j=0..3).
// Swizzled x-tile; w reads are wave-broadcast. Writes f64 partials.
__global__ __launch_bounds__(256) void convd_f64_v5(
    const double* __restrict__ x2,    // [nb][256][T]
    const double* __restrict__ wdt,   // [(ci*24+k)][128]
    double* __restrict__ parts,       // [nsplit][nb][128][341]
    int nb, int nsplit, int cis)
{
    const int bz  = blockIdx.z;
    const int s   = bz % nsplit;
    const int b   = bz / nsplit;
    const int co0 = blockIdx.y * 64;
    const int tp0 = blockIdx.x * 128;
    const int tid = threadIdx.x;
    const int tcol = tid & 31;
    const int crow = tid >> 5;

    __shared__ double xs[2][1552];    // 24832 B (span 127*12+24=1548, swizzled)
    __shared__ double wsh[48][64];    // 24576 B

    double acc[8][4];
    #pragma unroll
    for (int i = 0; i < 8; ++i)
        #pragma unroll
        for (int j = 0; j < 4; ++j) acc[i][j] = 0.0;

    const int tbase = tp0 * 12 - 6;
    const int ci_begin = s * cis;

    for (int c0 = ci_begin; c0 < ci_begin + cis; c0 += 2) {
        for (int i = tid; i < 2 * 1548; i += 256) {
            int ci = i / 1548, col = i % 1548;
            int t = tbase + col;
            double v = (t >= 0 && t < T_)
                ? x2[((size_t)(b * 256 + c0 + ci)) * T_ + t] : 0.0;
            xs[ci][swz_scalar(col)] = v;
        }
        for (int i = tid; i < 48 * 64; i += 256) {
            int r = i >> 6, c = i & 63;
            wsh[r][c] = wdt[(size_t)(c0 * 24 + r) * 128 + co0 + c];
        }
        __syncthreads();

        #pragma unroll
        for (int ci = 0; ci < 2; ++ci) {
            #pragma unroll
            for (int kk = 0; kk < 12; ++kk) {
                const double* wr0 = &wsh[ci * 24 + 2 * kk][crow * 8];
                const double* wr1 = &wsh[ci * 24 + 2 * kk + 1][crow * 8];
                double2 xp[4];
                #pragma unroll
                for (int j = 0; j < 4; ++j) {
                    // col = (tcol+32j)*12 + 2kk  ->  bw = (tcol+32j)*6 + kk
                    int bw = (tcol + 32 * j) * 6 + kk;
                    int colp = ((bw ^ ((bw >> 3) & 7)) << 1);
                    xp[j] = *(const double2*)&xs[ci][colp];
                }
                #pragma unroll
                for (int i = 0; i < 8; ++i) {
                    double wa = wr0[i], wb = wr1[i];
                    #pragma unroll
                    for (int j = 0; j < 4; ++j) {
                        acc[i][j] = fma(wa, xp[j].x, acc[i][j]);
                        acc[i][j] = fma(wb, xp[j].y, acc[i][j]);
                    }
                }
            }
        }
        __syncthreads();
    }

    #pragma unroll
    for (int i = 0; i < 8; ++i) {
        int co = co0 + crow * 8 + i;
        #pragma unroll
        for (int j = 0; j < 4; ++j) {
            int tp = tp0 + tcol + 32 * j;
            if (tp < TP)
                parts[(((size_t)s * nb + b) * EMB + co) * TP + tp] = acc[i][j];
        }
    }
}

// ---------------- combine partials + bias -> ed (f64) + e_out (f32) ----------------
__global__ __launch_bounds__(256) void convd_combine(
    const double* __restrict__ parts, // [nsplit][nb][128][341]
    const float* __restrict__ bd,
    double* __restrict__ ed,          // [16][128][341] (absolute b)
    float* __restrict__ e_out,        // [16][128][341]
    int nb, int b_off, int nsplit)
{
    int idx = blockIdx.x * 256 + threadIdx.x;
    int total = nb * EMB * TP;
    if (idx >= total) return;
    int b_local = idx / (EMB * TP);
    int rem = idx % (EMB * TP);
    int co = rem / TP;
    size_t stride = (size_t)nb * EMB * TP;
    double y = 0.0;
    for (int s = 0; s < nsplit; ++s)     // ascending s: deterministic
        y += parts[(size_t)s * stride + idx];
    y += (double)bd[co];
    size_t o = (size_t)(b_off + b_local) * EMB * TP + rem;
    ed[o] = y;
    e_out[o] = (float)y;
}

// ---------------- f64 1x1 projection ----------------
__global__ __launch_bounds__(128) void zproj_f64(
    const double* __restrict__ ed,    // [B][128][341]
    const double* __restrict__ wpd,   // [16][128]
    const double* __restrict__ bpd,   // [16]
    double* __restrict__ z)           // [B][341][16]
{
    const int b = blockIdx.y;
    const int t = blockIdx.x * 128 + threadIdx.x;
    __shared__ double wps[16][128];
    for (int i = threadIdx.x; i < 16 * 128; i += 128)
        wps[i >> 7][i & 127] = wpd[i];
    __syncthreads();
    if (t >= TP) return;
    double acc[16];
    #pragma unroll
    for (int v = 0; v < 16; ++v) acc[v] = bpd[v];
    for (int co = 0; co < 128; ++co) {
        double x = ed[((size_t)(b * EMB + co)) * TP + t];
        #pragma unroll
        for (int v = 0; v < 16; ++v) acc[v] = fma(x, wps[v][co], acc[v]);
    }
    #pragma unroll
    for (int v = 0; v < 16; ++v)
        z[((size_t)(b * TP + t)) * 16 + v] = acc[v];
}

// ---------------- RVQ: f64 distances, wave-shuffle argmin ----------------
__global__ __launch_bounds__(256) void rvq_f64_v2(
    const double* __restrict__ z,     // [NPOS][16]
    const float* __restrict__ cb,     // [8][256][16]
    float* __restrict__ out_idx)      // [8][NPOS] as float
{
    const int pos = blockIdx.x;
    const int tid = threadIdx.x;
    const int lane = tid & 63;
    const int wv = tid >> 6;

    __shared__ double r[16];
    __shared__ double wd_s[4];
    __shared__ int wi_s[4];
    __shared__ int best_s;

    if (tid < 16) r[tid] = z[(size_t)pos * 16 + tid];
    __syncthreads();

    for (int q = 0; q < NQ_; ++q) {
        const float* c = cb + ((size_t)(q * KCB) + tid) * 16;
        double d = 0.0;
        #pragma unroll
        for (int i = 0; i < 16; ++i) {
            double diff = r[i] - (double)c[i];
            d = fma(diff, diff, d);
        }
        int idx = tid;
        #pragma unroll
        for (int sft = 32; sft > 0; sft >>= 1) {
            double d2 = __shfl_down(d, sft, 64);
            int i2 = __shfl_down(idx, sft, 64);
            if (d2 < d || (d2 == d && i2 < idx)) { d = d2; idx = i2; }
        }
        if (lane == 0) { wd_s[wv] = d; wi_s[wv] = idx; }
        __syncthreads();
        if (tid == 0) {
            double bd_ = wd_s[0]; int bi = wi_s[0];
            #pragma unroll
            for (int w = 1; w < 4; ++w) {
                if (wd_s[w] < bd_ || (wd_s[w] == bd_ && wi_s[w] < bi)) {
                    bd_ = wd_s[w]; bi = wi_s[w];
                }
            }
            best_s = bi;
            out_idx[(size_t)q * NPOS + pos] = (float)bi;
        }
        __syncthreads();
        int best = best_s;
        if (tid < 16)
            r[tid] = r[tid] - (double)cb[((size_t)(q * KCB) + best) * 16 + tid];
        __syncthreads();
    }
}

// ---------------- host launcher ----------------
extern "C" void kernel_launch(void* const* d_in, const int* in_sizes, int n_in,
                              void* d_out, int out_size, void* d_ws, size_t ws_size,
                              hipStream_t stream) {
    const float* mel = (const float*)d_in[0];
    const float* w1  = (const float*)d_in[1];
    const float* b1  = (const float*)d_in[2];
    const float* g1  = (const float*)d_in[3];
    const float* be1 = (const float*)d_in[4];
    const float* m1  = (const float*)d_in[5];
    const float* v1  = (const float*)d_in[6];
    const float* w2  = (const float*)d_in[7];
    const float* b2  = (const float*)d_in[8];
    const float* g2  = (const float*)d_in[9];
    const float* be2 = (const float*)d_in[10];
    const float* m2  = (const float*)d_in[11];
    const float* v2  = (const float*)d_in[12];
    const float* wd  = (const float*)d_in[13];
    const float* bd  = (const float*)d_in[14];
    const float* wp  = (const float*)d_in[15];
    const float* bp  = (const float*)d_in[16];
    const float* cb  = (const float*)d_in[17];

    auto need = [](int nb, int ns) -> size_t {
        size_t s = 0;
        s += (size_t)BCH * C_ * T_ * 8;                 // x1
        s += (size_t)nb * C_ * T_ * 8;                  // x2
        s += (size_t)80*5*256*8 + (size_t)256*5*256*8 + (size_t)256*24*128*8;
        s += 4 * 2048 + 16384 + 256;                    // BN/proj scalars
        s += (size_t)16 * EMB * TP * 8;                 // ed
        s += (size_t)16 * TP * 16 * 8;                  // zd
        s += (size_t)ns * nb * EMB * TP * 8;            // parts
        s += 16384;                                     // align slack
        return s;
    };
    int nb = 8, nsplit = 8;
    if (ws_size >= need(16, 8))      { nb = 16; nsplit = 8; }
    else if (ws_size >= need(16, 4)) { nb = 16; nsplit = 4; }
    const int ngrp = B_ / nb;
    const int cis  = 256 / nsplit;

    char* ws = (char*)d_ws;
    size_t off = 0;
    auto alloc = [&](size_t bytes) -> char* {
        char* p = ws + off;
        off = (off + bytes + 255) & ~(size_t)255;
        return p;
    };
    double* x1d  = (double*)alloc((size_t)BCH * C_ * T_ * 8);
    double* x2d  = (double*)alloc((size_t)nb * C_ * T_ * 8);
    double* w1td = (double*)alloc((size_t)80*5*256*8);
    double* w2td = (double*)alloc((size_t)256*5*256*8);
    double* wdtd = (double*)alloc((size_t)256*24*128*8);
    double* a1d  = (double*)alloc(2048);
    double* bt1d = (double*)alloc(2048);
    double* a2d  = (double*)alloc(2048);
    double* bt2d = (double*)alloc(2048);
    double* wpd  = (double*)alloc(16*128*8);
    double* bpd  = (double*)alloc(16*8);
    double* ed   = (double*)alloc((size_t)16 * EMB * TP * 8);
    double* zd   = (double*)alloc((size_t)16 * TP * 16 * 8);
    double* parts= (double*)alloc((size_t)nsplit * nb * EMB * TP * 8);

    float* e_out   = (float*)d_out;                          // [16][128][341]
    float* idx_out = (float*)d_out + (size_t)B_ * EMB * TP;  // [8][16][341]

    prep_f64<<<3072, 256, 0, stream>>>(w1, w2, wd, b1, g1, be1, m1, v1,
                                       b2, g2, be2, m2, v2, wp, bp,
                                       w1td, w2td, wdtd, a1d, bt1d, a2d, bt2d,
                                       wpd, bpd);

    const int comb_blocks = (nb * EMB * TP + 255) / 256;
    for (int g = 0; g < ngrp; ++g) {
        for (int ch = 0; ch < nb / BCH; ++ch) {
            int ch_abs = g * (nb / BCH) + ch;
            const float* mel_c = mel + (size_t)ch_abs * BCH * CIN1 * T_;
            conv5_bn_relu_f64<CIN1, float><<<dim3(32, 4, BCH), 256, 0, stream>>>(
                mel_c, w1td, a1d, bt1d, x1d);
            conv5_bn_relu_f64<C_, double><<<dim3(32, 4, BCH), 256, 0, stream>>>(
                x1d, w2td, a2d, bt2d, x2d + (size_t)ch * BCH * C_ * T_);
        }
        convd_f64_v5<<<dim3(3, 2, nb * nsplit), 256, 0, stream>>>(
            x2d, wdtd, parts, nb, nsplit, cis);
        convd_combine<<<comb_blocks, 256, 0, stream>>>(parts, bd, ed, e_out,
                                                       nb, g * nb, nsplit);
    }
    zproj_f64<<<dim3(3, 16), 128, 0, stream>>>(ed, wpd, bpd, zd);
    rvq_f64_v2<<<NPOS, 256, 0, stream>>>(zd, cb, idx_out);
}